// Round 6
// baseline (196.740 us; speedup 1.0000x reference)
//
#include <hip/hip_runtime.h>
#include <hip/hip_bf16.h>
#include <stdint.h>

// WeightOnlyPerChannelQuantizedLinear: out[b,n] = (sum_k x[b,k]*w[n,k]) * scale[n]
// x: fp32 [16][8192], w: int8-valued int32 [28672][8192], scale: fp32 [28672]
//
// R6 vs R5 (191us, 4.9 TB/s): the per-window drain stall. R5 issued loads and
// consumed them within the same window (latency 900+cy > window compute ~400cy
// -> ~500cy stall/window). Fixes:
//  1. depth-2 register prefetch: window m issues loads for m+2; pack of m+1
//     waits on loads issued a full window earlier (latency fully hidden).
//  2. single-row 1KB-contiguous load instructions (was 4 rows x 256B) for
//     DRAM page locality.
//  3. afrag loads FIFO-ordered between st and st2 so no wait drains the
//     deep prefetch.

using f32x4 = __attribute__((ext_vector_type(4))) float;
using s16x8 = __attribute__((ext_vector_type(8))) short;
using i32x4 = __attribute__((ext_vector_type(4))) int;

static constexpr int K      = 8192;
static constexpr int N      = 28672;
static constexpr int NSTEPS = K / 32;     // 256 MFMA k-steps total
static constexpr int WK     = 512;        // k per window
static constexpr int NWIN   = K / WK;     // 16 windows
static constexpr int WAVES  = 4;
static constexpr int SPW    = (WK / 32) / WAVES;  // 4 MFMA steps/wave/window
static constexpr int LPB    = 16384;      // 16 rows * 512k * 2B per buffer

// ---------------------------------------------------------------------------
// Pre-pass (R1 mapping): lane l=(q<<4)|row of step kk holds A[row][kk*32+q*8+j],
// j=0..7, packed 4 dwords (even j low half), at afrag[kk*64 + l].
// ---------------------------------------------------------------------------
__global__ __launch_bounds__(256) void prep_a_kernel(const float* __restrict__ act,
                                                     uint4* __restrict__ afrag) {
  const int t   = blockIdx.x * 256 + threadIdx.x;
  const int kk  = t >> 6;
  const int l   = t & 63;
  const int row = l & 15;
  const int q   = l >> 4;
  const float* src = act + row * K + kk * 32 + q * 8;
  uint d[4];
#pragma unroll
  for (int p = 0; p < 4; ++p) {
    uint u0 = __builtin_bit_cast(uint, src[2 * p]);
    uint u1 = __builtin_bit_cast(uint, src[2 * p + 1]);
    u0 += 0x7fffu + ((u0 >> 16) & 1u);            // RNE f32 -> bf16
    u1 += 0x7fffu + ((u1 >> 16) & 1u);
    d[p] = (u0 >> 16) | (u1 & 0xffff0000u);
  }
  afrag[t] = make_uint4(d[0], d[1], d[2], d[3]);
}

__device__ __forceinline__ uint pack_bf16(int a, int b) {
  uint fa = __builtin_bit_cast(uint, (float)a);
  uint fb = __builtin_bit_cast(uint, (float)b);
  return (fa >> 16) | (fb & 0xffff0000u);   // exact for |w|<=127
}

// ---------------------------------------------------------------------------
// Main kernel. Block = 16 channels x full K, 4 waves, split-k 4x within block.
// Loader: wave w owns rows w*4..w*4+3. Per window 8 instrs; instr (rr,h):
//   all 64 lanes read 1KB contiguous of row w*4+rr, half h (lane l: 16B at
//   ints [m*512 + h*256 + l*4]).  LDS (bf16): byte (row*1024 + k*2) ^
//   ((row&7)<<4)  [XOR swizzle, G4].
// Pipeline per window m (unroll 2, st/st2 ping-pong):
//   LOADA(m) -> LOADW(st2, m+2) -> PACK(st = m+1) -> COMPUTE(m) -> barrier.
// FIFO: [st(m+1)][ag(m)][st2(m+2)]: pack waits st (1 window old, covered);
// compute waits ag only; st2 never drained.
// ---------------------------------------------------------------------------
__global__ __launch_bounds__(256, 4) void wq_linear_kernel(
    const int* __restrict__ wt,        // int32 [N][K]
    const uint4* __restrict__ afrag,   // [NSTEPS][64]
    const float* __restrict__ scaler,  // [N]
    float* __restrict__ out) {         // [16][N]
  __shared__ unsigned char lds[2][LPB];   // 32KB; buf0 reused for reduce
  const int tid = threadIdx.x;
  const int l   = tid & 63;
  const int w   = tid >> 6;
  const int n0  = blockIdx.x << 4;
  const int r   = l & 15;           // compute: B column (channel within tile)
  const int q   = l >> 4;           // compute: k-chunk selector

  const int* gw = wt + (size_t)(n0 + (w << 2)) * K + (l << 2);
  const int  rowbase = w << 2;

  i32x4 st[8], st2[8];
  uint4 ag[SPW];
  f32x4 acc = {0.f, 0.f, 0.f, 0.f};

#define LOADW(dst, m)                                                      \
  _Pragma("unroll") for (int j = 0; j < 8; ++j) {                          \
    const int rr = j >> 1, h = j & 1;                                      \
    dst[j] = *(const i32x4*)(gw + rr * K + (m) * WK + h * 256);            \
  }

#define PACKW(s, bi)                                                       \
  _Pragma("unroll") for (int j = 0; j < 8; ++j) {                          \
    const int rr = j >> 1, h = j & 1;                                      \
    const int row = rowbase + rr;                                          \
    const int ad = ((row << 10) + (h << 9) + (l << 3)) ^ ((row & 7) << 4); \
    uint2 v = {pack_bf16(s[j].x, s[j].y), pack_bf16(s[j].z, s[j].w)};      \
    *(uint2*)(&lds[bi][ad]) = v;                                           \
  }

  // prologue: window 0 staged, window 1 in regs
  LOADW(st, 0)
  PACKW(st, 0)
  LOADW(st, 1)
  __syncthreads();

#pragma unroll 2
  for (int m = 0; m < NWIN; ++m) {
    // afrag for window m (L2-resident; FIFO-ordered before st2)
#pragma unroll
    for (int s = 0; s < SPW; ++s)
      ag[s] = afrag[(size_t)((m << 4) + (w << 2) + s) * 64 + l];

    if (m + 2 < NWIN) { LOADW(st2, m + 2) }

    if (m + 1 < NWIN) { PACKW(st, (m + 1) & 1) }

    // compute window m: steps w*4..w*4+3
    const unsigned char* buf = lds[m & 1];
#pragma unroll
    for (int s = 0; s < SPW; ++s) {
      const int stp = (w << 2) + s;
      const int rb  = ((r << 10) + (stp << 6) + (q << 4)) ^ ((r & 7) << 4);
      const uint4 bv = *(const uint4*)(&buf[rb]);
      s16x8 a = __builtin_bit_cast(s16x8, ag[s]);
      s16x8 b = __builtin_bit_cast(s16x8, bv);
      acc = __builtin_amdgcn_mfma_f32_16x16x32_bf16(a, b, acc, 0, 0, 0);
    }

#pragma unroll
    for (int j = 0; j < 8; ++j) st[j] = st2[j];
    __syncthreads();
  }

  // epilogue: reduce 4 waves' split-k partials (reuse lds as f32 scratch)
  float* red = (float*)&lds[0][0];
  // acc layout (m89-verified): col = r, row(batch) = q*4 + i
#pragma unroll
  for (int i = 0; i < 4; ++i)
    red[w * 256 + ((q << 2) + i) * 16 + r] = acc[i];
  __syncthreads();

  const float sum = red[0 * 256 + tid] + red[1 * 256 + tid] +
                    red[2 * 256 + tid] + red[3 * 256 + tid];
  const int col = tid & 15;
  const int row = tid >> 4;
  out[(size_t)row * N + n0 + col] = sum * scaler[n0 + col];
}

extern "C" void kernel_launch(void* const* d_in, const int* in_sizes, int n_in,
                              void* d_out, int out_size, void* d_ws, size_t ws_size,
                              hipStream_t stream) {
  const float* act    = (const float*)d_in[0];
  const int*   wt     = (const int*)d_in[1];
  const float* scaler = (const float*)d_in[2];
  float*       out    = (float*)d_out;
  uint4*       afrag  = (uint4*)d_ws;   // 256 KB of A-fragments

  prep_a_kernel<<<(NSTEPS * 64) / 256, 256, 0, stream>>>(act, afrag);
  wq_linear_kernel<<<N / 16, 256, 0, stream>>>(wt, afrag, scaler, out);
}

// Round 7
// 193.340 us; speedup vs baseline: 1.0176x; 1.0176x over previous
//
#include <hip/hip_runtime.h>
#include <hip/hip_bf16.h>
#include <stdint.h>

// WeightOnlyPerChannelQuantizedLinear: out[b,n] = (sum_k x[b,k]*w[n,k]) * scale[n]
// x: fp32 [16][8192], w: int8-valued int32 [28672][8192], scale: fp32 [28672]
//
// R7 theory: R5/R6's per-window __syncthreads forces a compiler-emitted
// s_waitcnt vmcnt(0) drain (m97 finding) -> memory pipe restarts cold every
// window (4.9 TB/s). R1/R4 (no barrier) had shallow dependent waits (4.4).
// Fill kernel: 6.5 TB/s at 3.5 waves/CU -> saturation = never-drain, not MLP.
// Fix: 1-wave blocks with private LDS dbuf (no barriers at all), weights via
// global_load_lds DMA, counted s_waitcnt vmcnt(16) (never 0 mid-loop), k-split
// across blocks with f32 HW atomics. Bank conflicts fixed by pre-swizzling the
// GLOBAL source lane (linear DMA dest + same involution on ds_read, m173).

using f32x4 = __attribute__((ext_vector_type(4))) float;
using s16x8 = __attribute__((ext_vector_type(8))) short;
using i32x4 = __attribute__((ext_vector_type(4))) int;

static constexpr int K      = 8192;
static constexpr int N      = 28672;
static constexpr int NSTEPS = K / 32;       // 256 MFMA k-steps total
static constexpr int WK     = 256;          // ints per row per window
static constexpr int KSPLIT = 4;            // k-split across blocks
static constexpr int KRANGE = K / KSPLIT;   // 2048 k per block
static constexpr int NWIN   = KRANGE / WK;  // 8 windows
static constexpr int SPW    = WK / 32;      // 8 MFMA steps per window

// ---------------------------------------------------------------------------
// Pre-pass (R1 mapping): lane l=(q<<4)|row of step kk holds A[row][kk*32+q*8+j],
// j=0..7, packed 4 dwords (even j low half), at afrag[kk*64 + l].
// ---------------------------------------------------------------------------
__global__ __launch_bounds__(256) void prep_a_kernel(const float* __restrict__ act,
                                                     uint4* __restrict__ afrag) {
  const int t   = blockIdx.x * 256 + threadIdx.x;
  const int kk  = t >> 6;
  const int l   = t & 63;
  const int row = l & 15;
  const int q   = l >> 4;
  const float* src = act + row * K + kk * 32 + q * 8;
  uint d[4];
#pragma unroll
  for (int p = 0; p < 4; ++p) {
    uint u0 = __builtin_bit_cast(uint, src[2 * p]);
    uint u1 = __builtin_bit_cast(uint, src[2 * p + 1]);
    u0 += 0x7fffu + ((u0 >> 16) & 1u);            // RNE f32 -> bf16
    u1 += 0x7fffu + ((u1 >> 16) & 1u);
    d[p] = (u0 >> 16) | (u1 & 0xffff0000u);
  }
  afrag[t] = make_uint4(d[0], d[1], d[2], d[3]);
}

__device__ __forceinline__ uint pack_bf16(int a, int b) {
  uint fa = __builtin_bit_cast(uint, (float)a);
  uint fb = __builtin_bit_cast(uint, (float)b);
  return (fa >> 16) | (fb & 0xffff0000u);   // exact for |w|<=127
}

// ---------------------------------------------------------------------------
// Main kernel. Grid (N/16, KSPLIT), block = 64 threads = ONE wave.
// Wave owns 16 channels x 2048 k; LDS = private [2][16][256] int32 (32 KB,
// 5 blocks/CU). Per window m:
//   issue 8 afrag loads (m) -> issue 16 global_load_lds (m+1, 1 KB/row/instr,
//   source lane ^ sperm(r)) -> s_waitcnt vmcnt(16) [keeps m+1's DMA in
//   flight] -> 8 steps of {2x swizzled ds_read_b128, pack int->bf16, MFMA}.
// NO __syncthreads anywhere. Epilogue: scale + unsafeAtomicAdd (out zeroed).
// Swizzle: physical = logical ^ (sperm(row)<<4), sperm(r)=((r&3)<<1)|((r>>2)&1)
// applied on BOTH global-source lane and ds_read address (involution, m173).
// ---------------------------------------------------------------------------
__global__ __launch_bounds__(64) void wq_linear_kernel(
    const int* __restrict__ wt,        // int32 [N][K]
    const uint4* __restrict__ afrag,   // [NSTEPS][64]
    const float* __restrict__ scaler,  // [N]
    float* __restrict__ out) {         // [16][N], pre-zeroed
  __shared__ int buf[2][16 * WK];      // 32 KB
  const int l  = threadIdx.x;          // 0..63
  const int c  = l & 15;               // channel within tile (B col, A row)
  const int q  = l >> 4;               // k-chunk selector
  const int n0 = blockIdx.x << 4;
  const int kb = blockIdx.y * KRANGE;
  const int step0 = kb >> 5;           // global MFMA step base

  // stage window mm into buf[bi]: one 1 KB DMA per row, linear LDS dest,
  // source 16B-chunk index = l ^ sperm(r)
#define STAGE(mm, bi)                                                        \
  _Pragma("unroll") for (int r = 0; r < 16; ++r) {                           \
    const int sp = ((r & 3) << 1) | ((r >> 2) & 1);                          \
    const int* gsrc = wt + (size_t)(n0 + r) * K + kb + (mm) * WK             \
                      + ((l ^ sp) << 2);                                     \
    __builtin_amdgcn_global_load_lds(                                        \
        (const __attribute__((address_space(1))) unsigned int*)gsrc,         \
        (__attribute__((address_space(3))) unsigned int*)&buf[bi][r * WK],   \
        16, 0, 0);                                                           \
  }

  STAGE(0, 0)

  f32x4 acc = {0.f, 0.f, 0.f, 0.f};
  const int spc = ((c & 3) << 1) | ((c >> 2) & 1);   // sperm(c)

#pragma unroll 1
  for (int m = 0; m < NWIN; ++m) {
    // A-fragments for window m (L2-resident; issued BEFORE next DMA batch so
    // vmcnt(16) retires them together with window m's DMA)
    uint4 ag[SPW];
#pragma unroll
    for (int s = 0; s < SPW; ++s)
      ag[s] = afrag[(size_t)(step0 + m * SPW + s) * 64 + l];

    if (m + 1 < NWIN) {
      STAGE(m + 1, (m + 1) & 1)
      asm volatile("s_waitcnt vmcnt(16)" ::: "memory");  // m+1 stays in flight
    } else {
      asm volatile("s_waitcnt vmcnt(0)" ::: "memory");   // tail drain
    }
    __builtin_amdgcn_sched_barrier(0);   // keep ds_reads below the wait

    const char* rowp = (const char*)&buf[m & 1][c * WK];
#pragma unroll
    for (int s = 0; s < SPW; ++s) {
      const int o0 = (s << 7) + (((q << 5) | 0)  ^ (spc << 4));
      const int o1 = (s << 7) + (((q << 5) | 16) ^ (spc << 4));
      const i32x4 w0 = *(const i32x4*)(rowp + o0);   // k = q*8 + 0..3
      const i32x4 w1 = *(const i32x4*)(rowp + o1);   // k = q*8 + 4..7
      const uint b0 = pack_bf16(w0.x, w0.y);
      const uint b1 = pack_bf16(w0.z, w0.w);
      const uint b2 = pack_bf16(w1.x, w1.y);
      const uint b3 = pack_bf16(w1.z, w1.w);
      s16x8 a = __builtin_bit_cast(s16x8, ag[s]);
      s16x8 b = __builtin_bit_cast(s16x8, make_uint4(b0, b1, b2, b3));
      acc = __builtin_amdgcn_mfma_f32_16x16x32_bf16(a, b, acc, 0, 0, 0);
    }
  }

  // acc layout (m89-verified): col = l&15, row(batch) = (l>>4)*4 + i
  const float scl = scaler[n0 + c];
#pragma unroll
  for (int i = 0; i < 4; ++i) {
    const int b = (q << 2) + i;
    unsafeAtomicAdd(&out[(size_t)b * N + n0 + c], acc[i] * scl);
  }
#undef STAGE
}

extern "C" void kernel_launch(void* const* d_in, const int* in_sizes, int n_in,
                              void* d_out, int out_size, void* d_ws, size_t ws_size,
                              hipStream_t stream) {
  const float* act    = (const float*)d_in[0];
  const int*   wt     = (const int*)d_in[1];
  const float* scaler = (const float*)d_in[2];
  float*       out    = (float*)d_out;
  uint4*       afrag  = (uint4*)d_ws;   // 256 KB of A-fragments

  hipMemsetAsync(out, 0, (size_t)out_size * sizeof(float), stream);
  prep_a_kernel<<<(NSTEPS * 64) / 256, 256, 0, stream>>>(act, afrag);
  dim3 grid(N / 16, KSPLIT);
  wq_linear_kernel<<<grid, 64, 0, stream>>>(wt, afrag, scaler, out);
}